// Round 1
// baseline (543.587 us; speedup 1.0000x reference)
//
#include <hip/hip_runtime.h>

// Match numpy rounding: no fma contraction anywhere in this file.
#pragma clang fp contract(off)

#define NCLS 22
#define HS 60
#define WS_ 80
#define P 4800          // HS*WS_
#define NBATCH 2
#define H 480
#define W 640
#define EPSF 1e-8f
#define NCHUNK 4
#define ICHUNK 1200     // P / NCHUNK

// ---------------- kernel A: gather subsampled label / u / v / z ----------------
__global__ void prep_kernel(const int* __restrict__ label,
                            const float* __restrict__ vp,
                            int* __restrict__ lab_s,
                            float* __restrict__ u_s,
                            float* __restrict__ v_s,
                            float* __restrict__ z_s) {
    int t = blockIdx.x * blockDim.x + threadIdx.x;
    if (t >= NBATCH * P) return;
    int n = t / P, p = t % P;
    int hs = p / WS_, ws = p % WS_;
    int y = hs * 8, x = ws * 8;
    int lab = label[((size_t)n * H + y) * W + x];
    lab_s[t] = lab;
    const size_t HW = (size_t)H * W;
    size_t base = ((size_t)n * (3 * NCLS) + 3 * lab) * HW + (size_t)y * W + x;
    u_s[t] = vp[base];
    v_s[t] = vp[base + HW];
    z_s[t] = vp[base + 2 * HW];
}

// ---------------- kernel B: vote + per-class histogram over centers j ----------
// grid: (P/64, NCHUNK, NBATCH), block: 64. Thread owns center j; loops pixels i.
__global__ void vote_kernel(const int* __restrict__ lab_s,
                            const float* __restrict__ u_s,
                            const float* __restrict__ v_s,
                            int* __restrict__ hough) {
    __shared__ int hist[NCLS][64];
    int tid = threadIdx.x;
    int j = blockIdx.x * 64 + tid;          // always < P (75*64 == 4800)
    int chunk = blockIdx.y;
    int n = blockIdx.z;
    for (int c = 0; c < NCLS; ++c) hist[c][tid] = 0;

    float pxj = (float)((j % WS_) * 8);
    float pyj = (float)((j / WS_) * 8);

    int i0 = chunk * ICHUNK, i1 = i0 + ICHUNK;
    for (int i = i0; i < i1; ++i) {
        int lab = lab_s[n * P + i];
        if (lab == 0) continue;             // wave-uniform branch
        float u = u_s[n * P + i];
        float v = v_s[n * P + i];
        float pxi = (float)((i % WS_) * 8);
        float pyi = (float)((i / WS_) * 8);
        float nrm = sqrtf(u * u + v * v) + EPSF;
        float dx = pxj - pxi;               // dx[i,j] = px[j] - px[i]
        float dy = pyj - pyi;
        float d2 = dx * dx + dy * dy;       // exact (small ints)
        float dist = sqrtf(d2);
        float num = u * dx + v * dy;
        float den = nrm * (dist + EPSF);
        float cosang = num / den;           // IEEE divide, matches numpy
        int vote = (cosang >= 0.9f) && (d2 > 0.0f);
        hist[lab][tid] += vote;
    }
    for (int c = 1; c < NCLS; ++c) {
        int h = hist[c][tid];
        if (h) atomicAdd(&hough[((size_t)n * NCLS + c) * P + j], h);
    }
}

// ---------------- kernel C: per-(n,c) argmax over j (first-max tie-break) ------
__global__ void argmax_kernel(const int* __restrict__ hough,
                              int* __restrict__ best,
                              float* __restrict__ maxv) {
    int row_id = blockIdx.x;                // n*NCLS + c
    const int* row = &hough[(size_t)row_id * P];
    int tid = threadIdx.x;                  // 256
    int bi = tid;                           // tid < P always
    int bv = row[bi];
    for (int jj = tid + 256; jj < P; jj += 256) {
        int v = row[jj];
        if (v > bv) { bv = v; bi = jj; }    // keeps smallest index within stride
    }
    __shared__ int sv[256], si[256];
    sv[tid] = bv; si[tid] = bi;
    __syncthreads();
    for (int s = 128; s > 0; s >>= 1) {
        if (tid < s) {
            int v2 = sv[tid + s], i2 = si[tid + s];
            if (v2 > sv[tid] || (v2 == sv[tid] && i2 < si[tid])) {
                sv[tid] = v2; si[tid] = i2;
            }
        }
        __syncthreads();
    }
    if (tid == 0) { best[row_id] = si[0]; maxv[row_id] = (float)sv[0]; }
}

// ---------------- kernel D: counts / inliers-at-best / z-mean / epilogue -------
__global__ void final_kernel(const int* __restrict__ lab_s,
                             const float* __restrict__ u_s,
                             const float* __restrict__ v_s,
                             const float* __restrict__ z_s,
                             const int* __restrict__ best,
                             const float* __restrict__ maxv,
                             const float* __restrict__ extents,
                             const float* __restrict__ meta,
                             float* __restrict__ out) {
    int row_id = blockIdx.x;                // n*NCLS + c
    int n = row_id / NCLS, c = row_id % NCLS;
    int b = best[row_id];
    float mv = maxv[row_id];
    float pxb = (float)((b % WS_) * 8);
    float pyb = (float)((b / WS_) * 8);
    int tid = threadIdx.x;                  // 256
    int cnt = 0, nin = 0;
    float zs = 0.0f;
    for (int i = tid; i < P; i += 256) {
        int lab = lab_s[n * P + i];
        if (lab != c) continue;
        cnt++;
        if (c == 0) continue;               // fg condition kills votes anyway
        float u = u_s[n * P + i];
        float v = v_s[n * P + i];
        float pxi = (float)((i % WS_) * 8);
        float pyi = (float)((i / WS_) * 8);
        float nrm = sqrtf(u * u + v * v) + EPSF;
        float dx = pxb - pxi;
        float dy = pyb - pyi;
        float d2 = dx * dx + dy * dy;
        float dist = sqrtf(d2);
        float num = u * dx + v * dy;
        float den = nrm * (dist + EPSF);
        float cosang = num / den;
        if ((cosang >= 0.9f) && (d2 > 0.0f)) {
            nin++;
            zs += z_s[n * P + i];
        }
    }
    __shared__ int sc[256], sn[256];
    __shared__ float sz[256];
    sc[tid] = cnt; sn[tid] = nin; sz[tid] = zs;
    __syncthreads();
    for (int s = 128; s > 0; s >>= 1) {
        if (tid < s) {
            sc[tid] += sc[tid + s];
            sn[tid] += sn[tid + s];
            sz[tid] += sz[tid + s];
        }
        __syncthreads();
    }
    if (tid == 0) {
        float cntf = (float)sc[0];
        float ninf = (float)sn[0];
        float z_mean = sz[0] / fmaxf(ninf, 1.0f);
        float zc = fmaxf(z_mean, 0.001f);
        bool valid = (cntf * 64.0f >= 500.0f) && (mv >= 10.0f)
                     && (mv >= 0.02f * cntf) && (c > 0);
        float vm = valid ? 1.0f : 0.0f;
        float fx  = meta[n * 9 + 0];
        float ppx = meta[n * 9 + 2];
        float fy  = meta[n * 9 + 4];
        float ppy = meta[n * 9 + 5];
        float ex = extents[c * 3 + 0];
        float ey = extents[c * 3 + 1];
        float bw = ex * fx / zc;
        float bh = ey * fy / zc;
        float cx = pxb, cy = pyb;
        float tx = (cx - ppx) * zc / fx;
        float ty = (cy - ppy) * zc / fy;
        float* box = out + (size_t)row_id * 7;
        box[0] = (float)n * vm;
        box[1] = (float)c * vm;
        box[2] = (cx - bw / 2.0f) * vm;
        box[3] = (cy - bh / 2.0f) * vm;
        box[4] = (cx + bw / 2.0f) * vm;
        box[5] = (cy + bh / 2.0f) * vm;
        box[6] = mv * vm;
        float* pose = out + (size_t)NBATCH * NCLS * 7 + (size_t)row_id * 7;
        pose[0] = vm;
        pose[1] = 0.0f;
        pose[2] = 0.0f;
        pose[3] = 0.0f;
        pose[4] = tx * vm;
        pose[5] = ty * vm;
        pose[6] = zc * vm;
    }
}

extern "C" void kernel_launch(void* const* d_in, const int* in_sizes, int n_in,
                              void* d_out, int out_size, void* d_ws, size_t ws_size,
                              hipStream_t stream) {
    const int*   label   = (const int*)d_in[0];     // (N,H,W) int32
    const float* vp      = (const float*)d_in[1];   // (N,66,H,W) f32
    const float* extents = (const float*)d_in[2];   // (22,3) f32
    // d_in[3] = poses (unused)
    const float* meta    = (const float*)d_in[4];   // (N,9) f32
    float* out = (float*)d_out;                     // 616 f32

    char* ws = (char*)d_ws;
    // layout (bytes): lab_s[9600]i32 | u_s | v_s | z_s | hough[2*22*4800]i32 | best[44]i32 | maxv[44]f32
    int*   lab_s = (int*)(ws + 0);
    float* u_s   = (float*)(ws + 38400);
    float* v_s   = (float*)(ws + 76800);
    float* z_s   = (float*)(ws + 115200);
    int*   hough = (int*)(ws + 153600);
    int*   best  = (int*)(ws + 153600 + 844800);
    float* maxv  = (float*)(ws + 153600 + 844800 + 176);

    hipMemsetAsync(hough, 0, (size_t)NBATCH * NCLS * P * sizeof(int), stream);

    prep_kernel<<<(NBATCH * P + 255) / 256, 256, 0, stream>>>(label, vp, lab_s, u_s, v_s, z_s);

    dim3 vgrid(P / 64, NCHUNK, NBATCH);
    vote_kernel<<<vgrid, 64, 0, stream>>>(lab_s, u_s, v_s, hough);

    argmax_kernel<<<NBATCH * NCLS, 256, 0, stream>>>(hough, best, maxv);

    final_kernel<<<NBATCH * NCLS, 256, 0, stream>>>(lab_s, u_s, v_s, z_s, best, maxv,
                                                    extents, meta, out);
}

// Round 2
// 280.350 us; speedup vs baseline: 1.9390x; 1.9390x over previous
//
#include <hip/hip_runtime.h>

// Match numpy rounding: no fma contraction anywhere in this file.
#pragma clang fp contract(off)

#define NCLS 22
#define WS_ 80
#define P 4800          // 60*80
#define NBATCH 2
#define H 480
#define W 640
#define EPSF 1e-8f

#define JTILES 19       // ceil(P/256)
#define ICHUNKS 25
#define ILEN 192        // P / ICHUNKS

// ---------------- kernel A: gather subsampled data + zero hough ----------------
// packed[t] = {u, v, nrm, bitcast(lab)};  z_s[t] = z
__global__ void prep_kernel(const int* __restrict__ label,
                            const float* __restrict__ vp,
                            float4* __restrict__ packed,
                            float* __restrict__ z_s,
                            int4* __restrict__ hough4) {
    int t = blockIdx.x * blockDim.x + threadIdx.x;
    // zero the hough accumulator (ws is poisoned 0xAA before every launch)
    const int nthreads = gridDim.x * blockDim.x;
    const int HTOT4 = NBATCH * NCLS * P / 4;    // 52800 int4
    for (int q = t; q < HTOT4; q += nthreads) hough4[q] = make_int4(0, 0, 0, 0);

    if (t >= NBATCH * P) return;
    int n = t / P, p = t % P;
    int hs = p / WS_, ws = p % WS_;
    int y = hs * 8, x = ws * 8;
    int lab = label[((size_t)n * H + y) * W + x];
    const size_t HW = (size_t)H * W;
    size_t base = ((size_t)n * (3 * NCLS) + 3 * lab) * HW + (size_t)y * W + x;
    float u = vp[base];
    float v = vp[base + HW];
    float z = vp[base + 2 * HW];
    float nrm = sqrtf(u * u + v * v) + EPSF;    // exact, same as reference
    packed[t] = make_float4(u, v, nrm, __int_as_float(lab));
    z_s[t] = z;
}

// ---------------- kernel B: vote + per-class histogram over centers j ----------
// grid (JTILES, ICHUNKS, NBATCH), block 256. Thread owns center j; loop over
// i-chunk staged in LDS (uniform broadcast reads).
__global__ void __launch_bounds__(256) vote_kernel(
        const float4* __restrict__ packed,
        int* __restrict__ hough) {
    __shared__ float4 sdat[ILEN];
    __shared__ int hist[NCLS][256];
    int tid = threadIdx.x;
    int j = blockIdx.x * 256 + tid;           // may be >= P in last tile
    int n = blockIdx.z;
    int i0 = blockIdx.y * ILEN;

    // stage the i-chunk
    if (tid < ILEN) sdat[tid] = packed[n * P + i0 + tid];
    for (int c = 0; c < NCLS; ++c) hist[c][tid] = 0;
    __syncthreads();

    int jc = j < P ? j : 0;
    float pxj = (float)((jc % WS_) * 8);
    float pyj = (float)((jc / WS_) * 8);

    #pragma unroll 2
    for (int ii = 0; ii < ILEN; ++ii) {
        float4 d = sdat[ii];
        int lab = __float_as_int(d.w);
        if (lab == 0) continue;               // uniform branch
        int i = i0 + ii;
        float pxi = (float)((i % WS_) * 8);
        float pyi = (float)((i / WS_) * 8);
        float dx = pxj - pxi;
        float dy = pyj - pyi;
        float d2 = dx * dx + dy * dy;         // exact (small ints)
        float dist = sqrtf(d2);
        float num = d.x * dx + d.y * dy;
        float den = d.z * (dist + EPSF);
        float cosang = num / den;             // IEEE divide, matches numpy
        int vote = (cosang >= 0.9f) && (d2 > 0.0f);
        hist[lab][tid] += vote;
    }
    __syncthreads();
    if (j < P) {
        for (int c = 1; c < NCLS; ++c) {
            int h = hist[c][tid];
            if (h) atomicAdd(&hough[((size_t)n * NCLS + c) * P + j], h);
        }
    }
}

// ---------------- kernel C: argmax + counts / inliers / z-mean / epilogue ------
__global__ void __launch_bounds__(256) final_kernel(
        const int* __restrict__ hough,
        const float4* __restrict__ packed,
        const float* __restrict__ z_s,
        const float* __restrict__ extents,
        const float* __restrict__ meta,
        float* __restrict__ out) {
    int row_id = blockIdx.x;                  // n*NCLS + c
    int n = row_id / NCLS, c = row_id % NCLS;
    int tid = threadIdx.x;                    // 256

    // --- phase 1: argmax over j (first-max tie-break, matches jnp.argmax) ---
    const int* row = &hough[(size_t)row_id * P];
    int bi = tid;
    int bv = row[bi];
    for (int jj = tid + 256; jj < P; jj += 256) {
        int v = row[jj];
        if (v > bv) { bv = v; bi = jj; }      // keeps smallest index per stride
    }
    __shared__ int sv[256], si[256];
    sv[tid] = bv; si[tid] = bi;
    __syncthreads();
    for (int s = 128; s > 0; s >>= 1) {
        if (tid < s) {
            int v2 = sv[tid + s], i2 = si[tid + s];
            if (v2 > sv[tid] || (v2 == sv[tid] && i2 < si[tid])) {
                sv[tid] = v2; si[tid] = i2;
            }
        }
        __syncthreads();
    }
    int b = si[0];
    float mv = (float)sv[0];
    __syncthreads();

    // --- phase 2: counts, inliers at best, z sum ---
    float pxb = (float)((b % WS_) * 8);
    float pyb = (float)((b / WS_) * 8);
    int cnt = 0, nin = 0;
    float zs = 0.0f;
    for (int i = tid; i < P; i += 256) {
        float4 d = packed[n * P + i];
        int lab = __float_as_int(d.w);
        if (lab != c) continue;
        cnt++;
        if (c == 0) continue;                 // fg condition kills votes anyway
        float pxi = (float)((i % WS_) * 8);
        float pyi = (float)((i / WS_) * 8);
        float dx = pxb - pxi;
        float dy = pyb - pyi;
        float d2 = dx * dx + dy * dy;
        float dist = sqrtf(d2);
        float num = d.x * dx + d.y * dy;
        float den = d.z * (dist + EPSF);
        float cosang = num / den;
        if ((cosang >= 0.9f) && (d2 > 0.0f)) {
            nin++;
            zs += z_s[n * P + i];
        }
    }
    __shared__ int sc[256], sn[256];
    __shared__ float sz[256];
    sc[tid] = cnt; sn[tid] = nin; sz[tid] = zs;
    __syncthreads();
    for (int s = 128; s > 0; s >>= 1) {
        if (tid < s) {
            sc[tid] += sc[tid + s];
            sn[tid] += sn[tid + s];
            sz[tid] += sz[tid + s];
        }
        __syncthreads();
    }
    if (tid == 0) {
        float cntf = (float)sc[0];
        float ninf = (float)sn[0];
        float z_mean = sz[0] / fmaxf(ninf, 1.0f);
        float zc = fmaxf(z_mean, 0.001f);
        bool valid = (cntf * 64.0f >= 500.0f) && (mv >= 10.0f)
                     && (mv >= 0.02f * cntf) && (c > 0);
        float vm = valid ? 1.0f : 0.0f;
        float fx  = meta[n * 9 + 0];
        float ppx = meta[n * 9 + 2];
        float fy  = meta[n * 9 + 4];
        float ppy = meta[n * 9 + 5];
        float ex = extents[c * 3 + 0];
        float ey = extents[c * 3 + 1];
        float bw = ex * fx / zc;
        float bh = ey * fy / zc;
        float cx = pxb, cy = pyb;
        float tx = (cx - ppx) * zc / fx;
        float ty = (cy - ppy) * zc / fy;
        float* box = out + (size_t)row_id * 7;
        box[0] = (float)n * vm;
        box[1] = (float)c * vm;
        box[2] = (cx - bw / 2.0f) * vm;
        box[3] = (cy - bh / 2.0f) * vm;
        box[4] = (cx + bw / 2.0f) * vm;
        box[5] = (cy + bh / 2.0f) * vm;
        box[6] = mv * vm;
        float* pose = out + (size_t)NBATCH * NCLS * 7 + (size_t)row_id * 7;
        pose[0] = vm;
        pose[1] = 0.0f;
        pose[2] = 0.0f;
        pose[3] = 0.0f;
        pose[4] = tx * vm;
        pose[5] = ty * vm;
        pose[6] = zc * vm;
    }
}

extern "C" void kernel_launch(void* const* d_in, const int* in_sizes, int n_in,
                              void* d_out, int out_size, void* d_ws, size_t ws_size,
                              hipStream_t stream) {
    const int*   label   = (const int*)d_in[0];     // (N,H,W) int32
    const float* vp      = (const float*)d_in[1];   // (N,66,H,W) f32
    const float* extents = (const float*)d_in[2];   // (22,3) f32
    // d_in[3] = poses (unused)
    const float* meta    = (const float*)d_in[4];   // (N,9) f32
    float* out = (float*)d_out;                     // 616 f32

    char* ws = (char*)d_ws;
    // layout (bytes): packed[9600]f4 (153600) | z_s[9600]f32 (38400) | hough[2*22*4800]i32 (844800)
    float4* packed = (float4*)(ws + 0);
    float*  z_s    = (float*)(ws + 153600);
    int*    hough  = (int*)(ws + 192000);

    prep_kernel<<<(NBATCH * P + 255) / 256, 256, 0, stream>>>(
        label, vp, packed, z_s, (int4*)hough);

    dim3 vgrid(JTILES, ICHUNKS, NBATCH);
    vote_kernel<<<vgrid, 256, 0, stream>>>(packed, hough);

    final_kernel<<<NBATCH * NCLS, 256, 0, stream>>>(hough, packed, z_s,
                                                    extents, meta, out);
}

// Round 3
// 274.253 us; speedup vs baseline: 1.9821x; 1.0222x over previous
//
#include <hip/hip_runtime.h>

// Match numpy rounding: no fma contraction anywhere in this file.
#pragma clang fp contract(off)

#define NCLS 22
#define WS_ 80
#define P 4800          // 60*80
#define NBATCH 2
#define H 480
#define W 640
#define EPSF 1e-8f

#define JTILES 19       // ceil(P/256)
#define ICHUNKS 50
#define ILEN 96         // P / ICHUNKS

// ---------------- kernel A: gather subsampled data + zero hough ----------------
// packed[t] = {u, v, nrm, bitcast(lab)};  pos[t] = {px, py};  z_s[t] = z
__global__ void prep_kernel(const int* __restrict__ label,
                            const float* __restrict__ vp,
                            float4* __restrict__ packed,
                            float2* __restrict__ pos,
                            float* __restrict__ z_s,
                            int4* __restrict__ hough4) {
    int t = blockIdx.x * blockDim.x + threadIdx.x;
    // zero the hough accumulator (ws is poisoned 0xAA before every launch)
    const int nthreads = gridDim.x * blockDim.x;
    const int HTOT4 = NBATCH * NCLS * P / 4;    // 52800 int4
    for (int q = t; q < HTOT4; q += nthreads) hough4[q] = make_int4(0, 0, 0, 0);

    if (t >= NBATCH * P) return;
    int n = t / P, p = t % P;
    int hs = p / WS_, ws = p % WS_;
    int y = hs * 8, x = ws * 8;
    int lab = label[((size_t)n * H + y) * W + x];
    const size_t HW = (size_t)H * W;
    size_t base = ((size_t)n * (3 * NCLS) + 3 * lab) * HW + (size_t)y * W + x;
    float u = vp[base];
    float v = vp[base + HW];
    float z = vp[base + 2 * HW];
    float nrm = sqrtf(u * u + v * v) + EPSF;    // exact, same as reference
    packed[t] = make_float4(u, v, nrm, __int_as_float(lab));
    pos[t] = make_float2((float)x, (float)y);   // exact small ints
    z_s[t] = z;
}

// ---------------- kernel B: vote + per-class histogram over centers j ----------
// grid (JTILES, ICHUNKS, NBATCH), block 256. Thread owns center j; loop over
// i-chunk staged in LDS (uniform broadcast reads, zero global loads in loop).
__global__ void __launch_bounds__(256) vote_kernel(
        const float4* __restrict__ packed,
        const float2* __restrict__ pos,
        int* __restrict__ hough) {
    __shared__ float4 sdat[ILEN];
    __shared__ float2 spos[ILEN];
    __shared__ unsigned short hist[NCLS][256];  // <=96 votes/thread, ushort safe
    int tid = threadIdx.x;
    int j = blockIdx.x * 256 + tid;           // may be >= P in last tile
    int n = blockIdx.z;
    int i0 = blockIdx.y * ILEN;

    if (tid < ILEN) {
        sdat[tid] = packed[n * P + i0 + tid];
        spos[tid] = pos[n * P + i0 + tid];
    }
    for (int c = 0; c < NCLS; ++c) hist[c][tid] = 0;
    __syncthreads();

    int jc = j < P ? j : 0;
    float pxj = (float)((jc % WS_) * 8);
    float pyj = (float)((jc / WS_) * 8);

    #pragma unroll 4
    for (int ii = 0; ii < ILEN; ++ii) {
        float4 d = sdat[ii];
        int lab = __float_as_int(d.w);
        if (lab == 0) continue;               // uniform branch
        float2 pp = spos[ii];
        float dx = pxj - pp.x;
        float dy = pyj - pp.y;
        float d2 = dx * dx + dy * dy;         // exact (small ints)
        float dist = sqrtf(d2);
        float num = d.x * dx + d.y * dy;
        float den = d.z * (dist + EPSF);
        float cosang = num / den;             // IEEE divide, matches numpy
        int vote = (cosang >= 0.9f) && (d2 > 0.0f);
        hist[lab][tid] += (unsigned short)vote;
    }
    __syncthreads();
    if (j < P) {
        for (int c = 1; c < NCLS; ++c) {
            int h = hist[c][tid];
            if (h) atomicAdd(&hough[((size_t)n * NCLS + c) * P + j], h);
        }
    }
}

// ---------------- kernel C: argmax + counts / inliers / z-mean / epilogue ------
__global__ void __launch_bounds__(256) final_kernel(
        const int* __restrict__ hough,
        const float4* __restrict__ packed,
        const float2* __restrict__ pos,
        const float* __restrict__ z_s,
        const float* __restrict__ extents,
        const float* __restrict__ meta,
        float* __restrict__ out) {
    int row_id = blockIdx.x;                  // n*NCLS + c
    int n = row_id / NCLS, c = row_id % NCLS;
    int tid = threadIdx.x;                    // 256

    // --- phase 1: argmax over j (first-max tie-break, matches jnp.argmax) ---
    const int* row = &hough[(size_t)row_id * P];
    int bi = tid;
    int bv = row[bi];
    for (int jj = tid + 256; jj < P; jj += 256) {
        int v = row[jj];
        if (v > bv) { bv = v; bi = jj; }      // keeps smallest index per stride
    }
    __shared__ int sv[256], si[256];
    sv[tid] = bv; si[tid] = bi;
    __syncthreads();
    for (int s = 128; s > 0; s >>= 1) {
        if (tid < s) {
            int v2 = sv[tid + s], i2 = si[tid + s];
            if (v2 > sv[tid] || (v2 == sv[tid] && i2 < si[tid])) {
                sv[tid] = v2; si[tid] = i2;
            }
        }
        __syncthreads();
    }
    int b = si[0];
    float mv = (float)sv[0];
    __syncthreads();

    // --- phase 2: counts, inliers at best, z sum ---
    float pxb = (float)((b % WS_) * 8);
    float pyb = (float)((b / WS_) * 8);
    int cnt = 0, nin = 0;
    float zs = 0.0f;
    for (int i = tid; i < P; i += 256) {
        float4 d = packed[n * P + i];
        int lab = __float_as_int(d.w);
        if (lab != c) continue;
        cnt++;
        if (c == 0) continue;                 // fg condition kills votes anyway
        float2 pp = pos[n * P + i];
        float dx = pxb - pp.x;
        float dy = pyb - pp.y;
        float d2 = dx * dx + dy * dy;
        float dist = sqrtf(d2);
        float num = d.x * dx + d.y * dy;
        float den = d.z * (dist + EPSF);
        float cosang = num / den;
        if ((cosang >= 0.9f) && (d2 > 0.0f)) {
            nin++;
            zs += z_s[n * P + i];
        }
    }
    __shared__ int sc[256], sn[256];
    __shared__ float sz[256];
    sc[tid] = cnt; sn[tid] = nin; sz[tid] = zs;
    __syncthreads();
    for (int s = 128; s > 0; s >>= 1) {
        if (tid < s) {
            sc[tid] += sc[tid + s];
            sn[tid] += sn[tid + s];
            sz[tid] += sz[tid + s];
        }
        __syncthreads();
    }
    if (tid == 0) {
        float cntf = (float)sc[0];
        float ninf = (float)sn[0];
        float z_mean = sz[0] / fmaxf(ninf, 1.0f);
        float zc = fmaxf(z_mean, 0.001f);
        bool valid = (cntf * 64.0f >= 500.0f) && (mv >= 10.0f)
                     && (mv >= 0.02f * cntf) && (c > 0);
        float vm = valid ? 1.0f : 0.0f;
        float fx  = meta[n * 9 + 0];
        float ppx = meta[n * 9 + 2];
        float fy  = meta[n * 9 + 4];
        float ppy = meta[n * 9 + 5];
        float ex = extents[c * 3 + 0];
        float ey = extents[c * 3 + 1];
        float bw = ex * fx / zc;
        float bh = ey * fy / zc;
        float cx = pxb, cy = pyb;
        float tx = (cx - ppx) * zc / fx;
        float ty = (cy - ppy) * zc / fy;
        float* box = out + (size_t)row_id * 7;
        box[0] = (float)n * vm;
        box[1] = (float)c * vm;
        box[2] = (cx - bw / 2.0f) * vm;
        box[3] = (cy - bh / 2.0f) * vm;
        box[4] = (cx + bw / 2.0f) * vm;
        box[5] = (cy + bh / 2.0f) * vm;
        box[6] = mv * vm;
        float* pose = out + (size_t)NBATCH * NCLS * 7 + (size_t)row_id * 7;
        pose[0] = vm;
        pose[1] = 0.0f;
        pose[2] = 0.0f;
        pose[3] = 0.0f;
        pose[4] = tx * vm;
        pose[5] = ty * vm;
        pose[6] = zc * vm;
    }
}

extern "C" void kernel_launch(void* const* d_in, const int* in_sizes, int n_in,
                              void* d_out, int out_size, void* d_ws, size_t ws_size,
                              hipStream_t stream) {
    const int*   label   = (const int*)d_in[0];     // (N,H,W) int32
    const float* vp      = (const float*)d_in[1];   // (N,66,H,W) f32
    const float* extents = (const float*)d_in[2];   // (22,3) f32
    // d_in[3] = poses (unused)
    const float* meta    = (const float*)d_in[4];   // (N,9) f32
    float* out = (float*)d_out;                     // 616 f32

    char* ws = (char*)d_ws;
    // layout (bytes): packed[9600]f4 (153600) | pos[9600]f2 (76800) |
    //                 z_s[9600]f32 (38400) | hough[2*22*4800]i32 (844800)
    float4* packed = (float4*)(ws + 0);
    float2* pos    = (float2*)(ws + 153600);
    float*  z_s    = (float*)(ws + 153600 + 76800);
    int*    hough  = (int*)(ws + 153600 + 76800 + 38400);

    prep_kernel<<<(NBATCH * P + 255) / 256, 256, 0, stream>>>(
        label, vp, packed, pos, z_s, (int4*)hough);

    dim3 vgrid(JTILES, ICHUNKS, NBATCH);
    vote_kernel<<<vgrid, 256, 0, stream>>>(packed, pos, hough);

    final_kernel<<<NBATCH * NCLS, 256, 0, stream>>>(hough, packed, pos, z_s,
                                                    extents, meta, out);
}